// Round 1
// baseline (245.406 us; speedup 1.0000x reference)
//
#include <hip/hip_runtime.h>
#include <math.h>

// B=4, S=4096, D=2048, E=64, K=2
#define NTOK    16384
#define DDIM    2048
#define NEXP    64
#define PSTRIDE (NTOK * NEXP)
#define WHALF   (NEXP * DDIM)        // 131072 halves per plane

typedef _Float16 half8   __attribute__((ext_vector_type(8)));
typedef float    floatx4 __attribute__((ext_vector_type(4)));

// ---------------------------------------------------------------------------
// W (fp32 [64][2048]) -> d_ws as two plain row-major f16 planes:
//   hi[e][k] = (f16)W[e][k]
//   lo[e][k] = (f16)((W[e][k] - (f32)hi[e][k]) * 2048)
// No swizzle needed: B fragments are read straight to registers now (no LDS).
// ---------------------------------------------------------------------------
__global__ __launch_bounds__(256) void wconv_kernel(
    const float* __restrict__ W, _Float16* __restrict__ ws)
{
    const int g   = blockIdx.x * 256 + threadIdx.x;   // 16384 threads x 8 elems
    const int e   = g >> 8;
    const int pos = (g & 255) * 8;

    const float* src = &W[(size_t)e * DDIM + pos];
    floatx4 w0 = *(const floatx4*)src;
    floatx4 w1 = *(const floatx4*)(src + 4);

    half8 hi, lo;
#pragma unroll
    for (int i = 0; i < 4; ++i) {
        float f0 = w0[i], f1 = w1[i];
        _Float16 h0 = (_Float16)f0, h1 = (_Float16)f1;
        hi[i]     = h0; lo[i]     = (_Float16)((f0 - (float)h0) * 2048.0f);
        hi[4 + i] = h1; lo[4 + i] = (_Float16)((f1 - (float)h1) * 2048.0f);
    }

    _Float16* dst = ws + (size_t)e * DDIM + pos;
    *(half8*)dst           = hi;
    *(half8*)(dst + WHALF) = lo;
}

// ---------------------------------------------------------------------------
// Fused router, barrier-free K-loop. Block = 32 tokens, 4 waves (t,h) =
// token-half x k-half. W-f16 planes (512 KB total) are L2-resident, so B
// fragments are loaded register-direct (16 B chunks, 64 B/row segments);
// t-pair duplication hits L1. x is prefetched 3 steps deep, B 2 steps deep;
// the compiler's count-based vmcnt keeps everything in flight -- no
// __syncthreads in the hot loop, so HBM requests stream continuously.
// ---------------------------------------------------------------------------
__global__ __launch_bounds__(256, 2) void router_kernel(
    const float* __restrict__ x,
    const _Float16* __restrict__ ws,
    const float* __restrict__ bias,
    float* __restrict__ out)
{
    __shared__ float rbuf[2048];       // 8 KB: h=1 -> h=0 logit reduce

    const int tid  = threadIdx.x;
    const int lane = tid & 63;
    const int wid  = tid >> 6;
    const int t    = wid >> 1;         // token half
    const int h    = wid & 1;          // k half
    const int t0   = blockIdx.x * 32 + t * 16;
    const int mrow = lane & 15;        // A token row / B expert row
    const int quad = lane >> 4;

    floatx4 acc_hh[4], acc_md[4];
#pragma unroll
    for (int j = 0; j < 4; ++j) { acc_hh[j] = (floatx4)0.0f; acc_md[j] = (floatx4)0.0f; }

    // step u (0..31): k = p*128 + h*64 + s*32 + quad*8, p=u>>1, s=u&1.
    // KOF masks out-of-range tail prefetches back in-bounds (data unused).
#define KOF(v) (((((v) >> 1) * 128) + (((v) & 1) * 32)) & (DDIM - 1))

    const float*    xrow = x  + (size_t)(t0 + mrow) * DDIM + h * 64 + quad * 8;
    const _Float16* whi  = ws + (size_t)mrow * DDIM        + h * 64 + quad * 8;
    const _Float16* wlo  = whi + WHALF;

#define LOADB(BH, BL, KOFF)                                                   \
    {                                                                         \
        const int _ko = (KOFF);                                               \
        _Pragma("unroll")                                                     \
        for (int j = 0; j < 4; ++j) {                                         \
            BH[j] = *(const half8*)(whi + j * (16 * DDIM) + _ko);             \
            BL[j] = *(const half8*)(wlo + j * (16 * DDIM) + _ko);             \
        }                                                                     \
    }

#define LOADX(X0, X1, KOFF)                                                   \
    {                                                                         \
        const int _ko = (KOFF);                                               \
        X0 = *(const floatx4*)(xrow + _ko);                                   \
        X1 = *(const floatx4*)(xrow + _ko + 4);                               \
    }

#define COMPUTE(X0, X1, BH, BL)                                               \
    {                                                                         \
        half8 a_hi, a_lo;                                                     \
        _Pragma("unroll")                                                     \
        for (int i = 0; i < 4; ++i) {                                         \
            float f0 = (X0)[i], f1 = (X1)[i];                                 \
            _Float16 h0 = (_Float16)f0, h1 = (_Float16)f1;                    \
            a_hi[i]     = h0; a_lo[i]     = (_Float16)((f0 - (float)h0) * 2048.0f); \
            a_hi[4 + i] = h1; a_lo[4 + i] = (_Float16)((f1 - (float)h1) * 2048.0f); \
        }                                                                     \
        _Pragma("unroll")                                                     \
        for (int j = 0; j < 4; ++j) {                                         \
            acc_hh[j] = __builtin_amdgcn_mfma_f32_16x16x32_f16(a_hi, (BH)[j], acc_hh[j], 0, 0, 0); \
            acc_md[j] = __builtin_amdgcn_mfma_f32_16x16x32_f16(a_hi, (BL)[j], acc_md[j], 0, 0, 0); \
            acc_md[j] = __builtin_amdgcn_mfma_f32_16x16x32_f16(a_lo, (BH)[j], acc_md[j], 0, 0, 0); \
        }                                                                     \
    }

    half8   bh0[4], bl0[4], bh1[4], bl1[4];
    floatx4 X0a, X0b, X1a, X1b, X2a, X2b, X3a, X3b;

    // prologue: x 3 steps deep, B 2 steps deep
    LOADX(X0a, X0b, KOF(0))
    LOADX(X1a, X1b, KOF(1))
    LOADX(X2a, X2b, KOF(2))
    LOADB(bh0, bl0, KOF(0))
    LOADB(bh1, bl1, KOF(1))

#pragma unroll 1
    for (int u = 0; u < 32; u += 4) {
        LOADX(X3a, X3b, KOF(u + 3))
        COMPUTE(X0a, X0b, bh0, bl0)          // step u
        LOADB(bh0, bl0, KOF(u + 2))

        LOADX(X0a, X0b, KOF(u + 4))
        COMPUTE(X1a, X1b, bh1, bl1)          // step u+1
        LOADB(bh1, bl1, KOF(u + 3))

        LOADX(X1a, X1b, KOF(u + 5))
        COMPUTE(X2a, X2b, bh0, bl0)          // step u+2
        LOADB(bh0, bl0, KOF(u + 4))

        LOADX(X2a, X2b, KOF(u + 6))
        COMPUTE(X3a, X3b, bh1, bl1)          // step u+3
        LOADB(bh1, bl1, KOF(u + 5))
    }

    // ---- combine planes, reduce h=1 -> h=0 through LDS ----
    float lg[4][4];
#pragma unroll
    for (int j = 0; j < 4; ++j)
#pragma unroll
        for (int r = 0; r < 4; ++r)
            lg[j][r] = acc_hh[j][r] + acc_md[j][r] * (1.0f / 2048.0f);

    if (h == 1) {
#pragma unroll
        for (int j = 0; j < 4; ++j)
#pragma unroll
            for (int r = 0; r < 4; ++r)
                rbuf[t * 1024 + (j * 4 + r) * 64 + lane] = lg[j][r];
    }
    __syncthreads();
    if (h == 1) return;

#pragma unroll
    for (int j = 0; j < 4; ++j) {
        const float bj = bias[j * 16 + mrow];
#pragma unroll
        for (int r = 0; r < 4; ++r)
            lg[j][r] += rbuf[t * 1024 + (j * 4 + r) * 64 + lane] + bj;
    }

    // ---- epilogue: lane owns tokens t0 + quad*4 + r, experts j*16 + mrow ----
    const int c = mrow;
#pragma unroll
    for (int r = 0; r < 4; ++r) {
        const int trow = t0 + quad * 4 + r;

        float m = lg[0][r];
#pragma unroll
        for (int j = 1; j < 4; ++j) m = fmaxf(m, lg[j][r]);
#pragma unroll
        for (int off = 1; off <= 8; off <<= 1) m = fmaxf(m, __shfl_xor(m, off));

        float pj[4], s = 0.0f;
#pragma unroll
        for (int j = 0; j < 4; ++j) { pj[j] = __expf(lg[j][r] - m); s += pj[j]; }
#pragma unroll
        for (int off = 1; off <= 8; off <<= 1) s += __shfl_xor(s, off);
        const float rinv = 1.0f / s;

        // stable top-2 on logits (tie -> lower expert index)
        float v1 = -1e30f, v2 = -1e30f; int i1 = -1, i2 = -1;
#pragma unroll
        for (int j = 0; j < 4; ++j) {
            float v = lg[j][r]; int e = j * 16 + c;
            if (v > v1 || (v == v1 && e < i1)) { v2 = v1; i2 = i1; v1 = v; i1 = e; }
            else if (v > v2 || (v == v2 && e < i2)) { v2 = v; i2 = e; }
        }
#pragma unroll
        for (int off = 1; off <= 8; off <<= 1) {
            float u1 = __shfl_xor(v1, off); int q1 = __shfl_xor(i1, off);
            float u2 = __shfl_xor(v2, off); int q2 = __shfl_xor(i2, off);
            if (u1 > v1 || (u1 == v1 && q1 < i1)) {
                if (v1 > u2 || (v1 == u2 && i1 < q2)) { v2 = v1; i2 = i1; }
                else                                   { v2 = u2; i2 = q2; }
                v1 = u1; i1 = q1;
            } else {
                if (u1 > v2 || (u1 == v2 && q1 < i2)) { v2 = u1; i2 = q1; }
            }
        }

#pragma unroll
        for (int j = 0; j < 4; ++j) {
            const int col = j * 16 + c;
            const size_t o = (size_t)trow * NEXP + col;
            out[o]           = (col == i1 || col == i2) ? 1.0f : 0.0f;
            out[PSTRIDE + o] = pj[j] * rinv;
        }
    }
}

extern "C" void kernel_launch(void* const* d_in, const int* in_sizes, int n_in,
                              void* d_out, int out_size, void* d_ws, size_t ws_size,
                              hipStream_t stream) {
    const float* x = (const float*)d_in[0];   // [4,4096,2048] f32
    const float* W = (const float*)d_in[1];   // [64,2048] f32
    const float* b = (const float*)d_in[2];   // [64] f32
    (void)in_sizes; (void)n_in; (void)out_size; (void)ws_size;
    float* out = (float*)d_out;               // [masks | probs]

    _Float16* ws = (_Float16*)d_ws;           // 2 planes x 256 KB = 512 KB

    hipLaunchKernelGGL(wconv_kernel, dim3(64), dim3(256), 0, stream, W, ws);
    hipLaunchKernelGGL(router_kernel, dim3(NTOK / 32), dim3(256), 0, stream, x, ws, b, out);
}

// Round 2
// 209.783 us; speedup vs baseline: 1.1698x; 1.1698x over previous
//
#include <hip/hip_runtime.h>
#include <math.h>

// B=4, S=4096, D=2048, E=64, K=2
#define NTOK    16384
#define DDIM    2048
#define NEXP    64
#define PSTRIDE (NTOK * NEXP)
#define NPH     32                 // phases of 64 k
#define WSLICE  16384              // W slice bytes: 2 planes x 64 e x 64 k x 2 B
#define XSLICE  8192               // x slice bytes: 32 tok x 64 k x 4 B
#define NBUF    3

#define AS1 __attribute__((address_space(1)))
#define AS3 __attribute__((address_space(3)))

typedef _Float16 half8   __attribute__((ext_vector_type(8)));
typedef float    floatx4 __attribute__((ext_vector_type(4)));

// ---------------------------------------------------------------------------
// W (fp32 [64][2048]) -> d_ws: 32 slices (64 k each) of 16 KB, stored in the
// exact linear order the router's DMA writes LDS, with XOR chunk swizzle:
// slice p, linear chunk L = plane*512 + e*8 + c', holding source k-chunk
// c = c' ^ (e&7), k = p*64 + c*8.  hi plane = (f16)w, lo = (f16)((w-hi)*2048).
// ---------------------------------------------------------------------------
__global__ __launch_bounds__(256) void wconv_kernel(
    const float* __restrict__ W, _Float16* __restrict__ ws)
{
    const int g     = blockIdx.x * 256 + threadIdx.x;   // 32768 chunks
    const int p     = g >> 10;
    const int L     = g & 1023;
    const int plane = L >> 9;
    const int e     = (L >> 3) & 63;
    const int cp    = L & 7;
    const int c     = cp ^ (e & 7);
    const int k     = (p << 6) + (c << 3);

    const float* src = &W[(size_t)e * DDIM + k];
    floatx4 w0 = *(const floatx4*)src;
    floatx4 w1 = *(const floatx4*)(src + 4);

    half8 o;
#pragma unroll
    for (int i = 0; i < 4; ++i) {
        float f0 = w0[i], f1 = w1[i];
        _Float16 h0 = (_Float16)f0, h1 = (_Float16)f1;
        if (plane == 0) { o[i] = h0; o[4 + i] = h1; }
        else {
            o[i]     = (_Float16)((f0 - (float)h0) * 2048.0f);
            o[4 + i] = (_Float16)((f1 - (float)h1) * 2048.0f);
        }
    }
    *(half8*)((char*)ws + (size_t)g * 16) = o;
}

// ---------------------------------------------------------------------------
// Fused router. Block = 32 tokens, 4 waves (t,h) = token-half x k-half.
// 32 phases of 64 k. BOTH W and x staged by coalesced global_load_lds into
// triple-buffered LDS, prefetched 2 phases ahead; counted s_waitcnt vmcnt(12)
// + raw s_barrier keeps DMA in flight across barriers (no vmcnt(0) drain in
// the loop). x LDS is XOR-swizzled (chunk ^ (row&15)) via pre-swizzled global
// source addresses; fragment ds_reads are bank-uniform.
// ---------------------------------------------------------------------------
__global__ __launch_bounds__(256, 2) void router_kernel(
    const float* __restrict__ x,
    const _Float16* __restrict__ ws,
    const float* __restrict__ bias,
    float* __restrict__ out)
{
    __shared__ _Float16 lw[NBUF * 8192];   // 3 x 16 KB
    __shared__ float    lx[NBUF * 2048];   // 3 x 8 KB

    const int tid  = threadIdx.x;
    const int lane = tid & 63;
    const int wid  = tid >> 6;
    const int t    = wid >> 1;         // token half
    const int h    = wid & 1;          // k half
    const int t0b  = blockIdx.x * 32;
    const int t0   = t0b + t * 16;
    const int mrow = lane & 15;        // A token row / B expert row
    const int quad = lane >> 4;

    floatx4 acc_hh[4], acc_md[4];
#pragma unroll
    for (int j = 0; j < 4; ++j) { acc_hh[j] = (floatx4)0.0f; acc_md[j] = (floatx4)0.0f; }

    // ---- DMA source pointers (advance by phase stride) ----
    // W: purely linear (ws is pre-swizzled): wave wid copies 4 KB.
    const char* gw = (const char*)ws + wid * 4096 + lane * 16;
    // x: this thread's two LDS chunks per phase: L = wid*128 + i*64 + lane.
    // row = L>>4, c' = L&15, source chunk c = c' ^ (row&15).
    const int L0 = wid * 128 + lane;
    const int L1 = L0 + 64;
    const int r0 = L0 >> 4, c0g = (L0 & 15) ^ (r0 & 15);
    const int r1 = L1 >> 4, c1g = (L1 & 15) ^ (r1 & 15);
    const char* gx0 = (const char*)(x + (size_t)(t0b + r0) * DDIM + c0g * 4);
    const char* gx1 = (const char*)(x + (size_t)(t0b + r1) * DDIM + c1g * 4);

#define STAGE(P, BUF)                                                          \
    {                                                                          \
        const char* gsw = gw + (size_t)(P) * WSLICE;                           \
        char*       ldw = (char*)lw + (BUF) * WSLICE + wid * 4096;             \
        _Pragma("unroll")                                                      \
        for (int i = 0; i < 4; ++i)                                            \
            __builtin_amdgcn_global_load_lds(                                  \
                (const AS1 unsigned int*)(const void*)(gsw + i * 1024),        \
                (AS3 unsigned int*)(void*)(ldw + i * 1024), 16, 0, 0);         \
        char* ldx = (char*)lx + (BUF) * XSLICE + wid * 2048;                   \
        __builtin_amdgcn_global_load_lds(                                      \
            (const AS1 unsigned int*)(const void*)(gx0 + (size_t)(P) * 256),   \
            (AS3 unsigned int*)(void*)(ldx), 16, 0, 0);                        \
        __builtin_amdgcn_global_load_lds(                                      \
            (const AS1 unsigned int*)(const void*)(gx1 + (size_t)(P) * 256),   \
            (AS3 unsigned int*)(void*)(ldx + 1024), 16, 0, 0);                 \
    }

#define COMPUTE(BUF)                                                           \
    {                                                                          \
        const _Float16* wb = lw + (BUF) * 8192;                                \
        const float*    xb = lx + (BUF) * 2048;                                \
        const int xrow = t * 16 + mrow;                                        \
        const int cc0  = h * 8 + quad * 2;                                     \
        floatx4 X0 = *(const floatx4*)(xb + xrow * 64 + ((cc0 ^ mrow) << 2));  \
        floatx4 X1 = *(const floatx4*)(xb + xrow * 64 + (((cc0 + 1) ^ mrow) << 2)); \
        half8 a_hi, a_lo;                                                      \
        _Pragma("unroll")                                                      \
        for (int i = 0; i < 4; ++i) {                                          \
            float f0 = X0[i], f1 = X1[i];                                      \
            _Float16 h0 = (_Float16)f0, h1 = (_Float16)f1;                     \
            a_hi[i]     = h0; a_lo[i]     = (_Float16)((f0 - (float)h0) * 2048.0f); \
            a_hi[4 + i] = h1; a_lo[4 + i] = (_Float16)((f1 - (float)h1) * 2048.0f); \
        }                                                                      \
        _Pragma("unroll")                                                      \
        for (int j = 0; j < 4; ++j) {                                          \
            const int e   = j * 16 + mrow;                                     \
            const int c   = h * 4 + quad;                                      \
            const int off = e * 64 + ((c ^ (e & 7)) << 3);                     \
            half8 bh = *(const half8*)(wb + off);                              \
            half8 bl = *(const half8*)(wb + 4096 + off);                       \
            acc_hh[j] = __builtin_amdgcn_mfma_f32_16x16x32_f16(a_hi, bh, acc_hh[j], 0, 0, 0); \
            acc_md[j] = __builtin_amdgcn_mfma_f32_16x16x32_f16(a_hi, bl, acc_md[j], 0, 0, 0); \
            acc_md[j] = __builtin_amdgcn_mfma_f32_16x16x32_f16(a_lo, bh, acc_md[j], 0, 0, 0); \
        }                                                                      \
    }

// One steady-state phase: barrier A (everyone done reading buf (P-1)%3, which
// (P+2) will overwrite) -> issue (P+2)'s 6 loads -> wait until P's loads are
// the newest-retired (12 newer in flight) -> barrier B -> compute P.
#define PHASE(P, BUF, BUF2)                                                    \
    {                                                                          \
        __builtin_amdgcn_s_barrier();                                          \
        asm volatile("" ::: "memory");                                         \
        STAGE(P + 2, BUF2)                                                     \
        asm volatile("s_waitcnt vmcnt(12)" ::: "memory");                      \
        __builtin_amdgcn_s_barrier();                                          \
        asm volatile("" ::: "memory");                                         \
        COMPUTE(BUF)                                                           \
    }

    // ---- prologue: 2 phases in flight ----
    STAGE(0, 0)
    STAGE(1, 1)

#pragma unroll 1
    for (int p3 = 0; p3 < NPH - 2; p3 += 3) {
        PHASE(p3 + 0, 0, 2)
        PHASE(p3 + 1, 1, 0)
        PHASE(p3 + 2, 2, 1)
    }
    // ---- tail: p = 30 (buf 0), p = 31 (buf 1); no more staging ----
    __builtin_amdgcn_s_barrier();
    asm volatile("" ::: "memory");
    asm volatile("s_waitcnt vmcnt(6)" ::: "memory");
    __builtin_amdgcn_s_barrier();
    asm volatile("" ::: "memory");
    COMPUTE(0)
    asm volatile("s_waitcnt vmcnt(0)" ::: "memory");
    __builtin_amdgcn_s_barrier();
    asm volatile("" ::: "memory");
    COMPUTE(1)

    // ---- combine planes, reduce h=1 -> h=0 through LDS ----
    float lg[4][4];
#pragma unroll
    for (int j = 0; j < 4; ++j)
#pragma unroll
        for (int r = 0; r < 4; ++r)
            lg[j][r] = acc_hh[j][r] + acc_md[j][r] * (1.0f / 2048.0f);

    float* rbuf = (float*)lw;          // 8 KB of buf0 region (phase 31 used buf1)
    if (h == 1) {
#pragma unroll
        for (int j = 0; j < 4; ++j)
#pragma unroll
            for (int r = 0; r < 4; ++r)
                rbuf[t * 1024 + (j * 4 + r) * 64 + lane] = lg[j][r];
    }
    __syncthreads();
    if (h == 1) return;

#pragma unroll
    for (int j = 0; j < 4; ++j) {
        const float bj = bias[j * 16 + mrow];
#pragma unroll
        for (int r = 0; r < 4; ++r)
            lg[j][r] += rbuf[t * 1024 + (j * 4 + r) * 64 + lane] + bj;
    }

    // ---- epilogue: lane owns tokens t0 + quad*4 + r, experts j*16 + mrow ----
    const int c = mrow;
#pragma unroll
    for (int r = 0; r < 4; ++r) {
        const int trow = t0 + quad * 4 + r;

        float m = lg[0][r];
#pragma unroll
        for (int j = 1; j < 4; ++j) m = fmaxf(m, lg[j][r]);
#pragma unroll
        for (int off = 1; off <= 8; off <<= 1) m = fmaxf(m, __shfl_xor(m, off));

        float pj[4], s = 0.0f;
#pragma unroll
        for (int j = 0; j < 4; ++j) { pj[j] = __expf(lg[j][r] - m); s += pj[j]; }
#pragma unroll
        for (int off = 1; off <= 8; off <<= 1) s += __shfl_xor(s, off);
        const float rinv = 1.0f / s;

        // stable top-2 on logits (tie -> lower expert index)
        float v1 = -1e30f, v2 = -1e30f; int i1 = -1, i2 = -1;
#pragma unroll
        for (int j = 0; j < 4; ++j) {
            float v = lg[j][r]; int e = j * 16 + c;
            if (v > v1 || (v == v1 && e < i1)) { v2 = v1; i2 = i1; v1 = v; i1 = e; }
            else if (v > v2 || (v == v2 && e < i2)) { v2 = v; i2 = e; }
        }
#pragma unroll
        for (int off = 1; off <= 8; off <<= 1) {
            float u1 = __shfl_xor(v1, off); int q1 = __shfl_xor(i1, off);
            float u2 = __shfl_xor(v2, off); int q2 = __shfl_xor(i2, off);
            if (u1 > v1 || (u1 == v1 && q1 < i1)) {
                if (v1 > u2 || (v1 == u2 && i1 < q2)) { v2 = v1; i2 = i1; }
                else                                   { v2 = u2; i2 = q2; }
                v1 = u1; i1 = q1;
            } else {
                if (u1 > v2 || (u1 == v2 && q1 < i2)) { v2 = u1; i2 = q1; }
            }
        }

#pragma unroll
        for (int j = 0; j < 4; ++j) {
            const int col = j * 16 + c;
            const size_t o = (size_t)trow * NEXP + col;
            out[o]           = (col == i1 || col == i2) ? 1.0f : 0.0f;
            out[PSTRIDE + o] = pj[j] * rinv;
        }
    }
}

extern "C" void kernel_launch(void* const* d_in, const int* in_sizes, int n_in,
                              void* d_out, int out_size, void* d_ws, size_t ws_size,
                              hipStream_t stream) {
    const float* x = (const float*)d_in[0];   // [4,4096,2048] f32
    const float* W = (const float*)d_in[1];   // [64,2048] f32
    const float* b = (const float*)d_in[2];   // [64] f32
    (void)in_sizes; (void)n_in; (void)out_size; (void)ws_size;
    float* out = (float*)d_out;               // [masks | probs]

    _Float16* ws = (_Float16*)d_ws;           // 32 slices x 16 KB = 512 KB

    hipLaunchKernelGGL(wconv_kernel, dim3(128), dim3(256), 0, stream, W, ws);
    hipLaunchKernelGGL(router_kernel, dim3(NTOK / 32), dim3(256), 0, stream, x, ws, b, out);
}

// Round 3
// 204.951 us; speedup vs baseline: 1.1974x; 1.0236x over previous
//
#include <hip/hip_runtime.h>
#include <math.h>

// B=4, S=4096, D=2048, E=64, K=2
#define NTOK    16384
#define DDIM    2048
#define NEXP    64
#define PSTRIDE (NTOK * NEXP)
#define NPH     16                 // phases of 128 k
#define WSLICE  32768              // W slice bytes: 2 planes x 64 e x 128 k x 2 B
#define XSLICE  32768              // x slice bytes: 64 tok x 128 k x 4 B

#define AS1 __attribute__((address_space(1)))
#define AS3 __attribute__((address_space(3)))

typedef _Float16 half8   __attribute__((ext_vector_type(8)));
typedef float    floatx4 __attribute__((ext_vector_type(4)));

// ---------------------------------------------------------------------------
// W (fp32 [64][2048]) -> d_ws: 16 slices (128 k each) of 32 KB, stored in the
// exact linear order the router's DMA writes LDS, with XOR chunk swizzle:
// slice p, linear chunk L = plane*1024 + e*16 + c', holding source k-chunk
// c = c' ^ (e&7), k = p*128 + c*8.  hi plane = (f16)w, lo = (f16)((w-hi)*2048).
// (identical layout to the round-0 kernel's wconv — known-good)
// ---------------------------------------------------------------------------
__global__ __launch_bounds__(256) void wconv_kernel(
    const float* __restrict__ W, _Float16* __restrict__ ws)
{
    const int g     = blockIdx.x * 256 + threadIdx.x;   // 32768 chunks total
    const int p     = g >> 11;
    const int L     = g & 2047;
    const int plane = L >> 10;
    const int e     = (L >> 4) & 63;
    const int cp    = L & 15;
    const int c     = cp ^ (e & 7);
    const int k     = (p << 7) + (c << 3);

    const float* src = &W[(size_t)e * DDIM + k];
    floatx4 w0 = *(const floatx4*)src;
    floatx4 w1 = *(const floatx4*)(src + 4);

    half8 o;
#pragma unroll
    for (int i = 0; i < 4; ++i) {
        float f0 = w0[i], f1 = w1[i];
        _Float16 h0 = (_Float16)f0, h1 = (_Float16)f1;
        if (plane == 0) { o[i] = h0; o[4 + i] = h1; }
        else {
            o[i]     = (_Float16)((f0 - (float)h0) * 2048.0f);
            o[4 + i] = (_Float16)((f1 - (float)h1) * 2048.0f);
        }
    }
    *(half8*)((char*)ws + (size_t)g * 16) = o;
}

// ---------------------------------------------------------------------------
// Fused router. Block = 64 tokens, 512 threads, 8 waves (t,h) = token-quarter
// x k-half. 16 phases of 128 k; W and x both staged by coalesced
// global_load_lds into double-buffered LDS (2 x 64 KB), prefetched 1 phase
// ahead; counted s_waitcnt vmcnt(8) + raw s_barrier keeps the next phase's
// DMA in flight across barriers. x LDS XOR-swizzled (chunk ^ (row&7)) via
// pre-swizzled per-lane global sources; all fragment ds_reads ~2-way max.
// 1 block/CU (128 KB LDS), halving W re-fetch vs 32-token blocks.
// ---------------------------------------------------------------------------
__global__ __launch_bounds__(512, 2) void router_kernel(
    const float* __restrict__ x,
    const _Float16* __restrict__ ws,
    const float* __restrict__ bias,
    float* __restrict__ out)
{
    __shared__ _Float16 lw[2][16384];   // 2 x 32 KB  (W slices)
    __shared__ float    lx[2][8192];    // 2 x 32 KB  (x slices)

    const int tid  = threadIdx.x;
    const int lane = tid & 63;
    const int wid  = tid >> 6;         // 0..7
    const int t    = wid >> 1;         // token quarter (16 rows)
    const int h    = wid & 1;          // k half of each 128-k phase
    const int t0b  = blockIdx.x * 64;
    const int t0   = t0b + t * 16;
    const int mrow = lane & 15;        // A token row / B expert row
    const int quad = lane >> 4;

    floatx4 acc_hh[4], acc_md[4];
#pragma unroll
    for (int j = 0; j < 4; ++j) { acc_hh[j] = (floatx4)0.0f; acc_md[j] = (floatx4)0.0f; }

    // ---- DMA source pointers ----
    // W: linear (ws pre-swizzled): wave wid copies 4 KB/phase (4 loads).
    const char* gwp = (const char*)ws + wid * 4096 + lane * 16;
    // x: per-lane pre-swizzled sources. LDS chunk L = wid*256 + i*64 + lane;
    // row = L>>5, c' = L&31, source chunk c = c' ^ (row&7).
    const char* gxp[4];
#pragma unroll
    for (int i = 0; i < 4; ++i) {
        const int L   = wid * 256 + i * 64 + lane;
        const int row = L >> 5;
        const int c   = (L & 31) ^ (row & 7);
        gxp[i] = (const char*)x + (size_t)(t0b + row) * (DDIM * 4) + c * 16;
    }

#define STAGE(P, BUF)                                                          \
    {                                                                          \
        const char* gsw = gwp + (size_t)(P) * WSLICE;                          \
        char*       ldw = (char*)&lw[BUF][0] + wid * 4096;                     \
        _Pragma("unroll")                                                      \
        for (int i = 0; i < 4; ++i)                                            \
            __builtin_amdgcn_global_load_lds(                                  \
                (const AS1 unsigned int*)(const void*)(gsw + i * 1024),        \
                (AS3 unsigned int*)(void*)(ldw + i * 1024), 16, 0, 0);         \
        char* ldx = (char*)&lx[BUF][0] + wid * 4096;                           \
        _Pragma("unroll")                                                      \
        for (int i = 0; i < 4; ++i)                                            \
            __builtin_amdgcn_global_load_lds(                                  \
                (const AS1 unsigned int*)(const void*)(gxp[i] + (size_t)(P) * 512), \
                (AS3 unsigned int*)(void*)(ldx + i * 1024), 16, 0, 0);         \
    }

#define COMPUTE(BUF)                                                           \
    {                                                                          \
        const _Float16* wb   = &lw[BUF][0];                                    \
        const float*    xb   = &lx[BUF][0];                                    \
        const int       arow = t * 16 + mrow;                                  \
        _Pragma("unroll")                                                      \
        for (int s = 0; s < 2; ++s) {                                          \
            const int cc0 = h * 16 + s * 8 + quad * 2;                         \
            floatx4 X0 = *(const floatx4*)(xb + arow * 128 + ((cc0 ^ (arow & 7)) << 2)); \
            floatx4 X1 = *(const floatx4*)(xb + arow * 128 + (((cc0 + 1) ^ (arow & 7)) << 2)); \
            half8 a_hi, a_lo;                                                  \
            _Pragma("unroll")                                                  \
            for (int i = 0; i < 4; ++i) {                                      \
                float f0 = X0[i], f1 = X1[i];                                  \
                _Float16 h0 = (_Float16)f0, h1 = (_Float16)f1;                 \
                a_hi[i]     = h0; a_lo[i]     = (_Float16)((f0 - (float)h0) * 2048.0f); \
                a_hi[4 + i] = h1; a_lo[4 + i] = (_Float16)((f1 - (float)h1) * 2048.0f); \
            }                                                                  \
            _Pragma("unroll")                                                  \
            for (int j = 0; j < 4; ++j) {                                      \
                const int e   = j * 16 + mrow;                                 \
                const int ck  = h * 8 + s * 4 + quad;                          \
                const int off = e * 128 + ((ck ^ (e & 7)) << 3);               \
                half8 bh = *(const half8*)(wb + off);                          \
                half8 bl = *(const half8*)(wb + 8192 + off);                   \
                acc_hh[j] = __builtin_amdgcn_mfma_f32_16x16x32_f16(a_hi, bh, acc_hh[j], 0, 0, 0); \
                acc_md[j] = __builtin_amdgcn_mfma_f32_16x16x32_f16(a_hi, bl, acc_md[j], 0, 0, 0); \
                acc_md[j] = __builtin_amdgcn_mfma_f32_16x16x32_f16(a_lo, bh, acc_md[j], 0, 0, 0); \
            }                                                                  \
        }                                                                      \
    }

    // ---- prologue: phase 0 in flight ----
    STAGE(0, 0)

#pragma unroll 1
    for (int p = 0; p < NPH; ++p) {
        if (p < NPH - 1) {
            STAGE(p + 1, (p + 1) & 1)           // issue next phase's 8 loads
            asm volatile("s_waitcnt vmcnt(8)" ::: "memory");   // phase p landed
        } else {
            asm volatile("s_waitcnt vmcnt(0)" ::: "memory");
        }
        __builtin_amdgcn_s_barrier();
        asm volatile("" ::: "memory");
        COMPUTE(p & 1)
        __builtin_amdgcn_s_barrier();           // everyone done reading buf
        asm volatile("" ::: "memory");
    }

    // ---- combine planes, reduce h=1 -> h=0 through LDS ----
    float lg[4][4];
#pragma unroll
    for (int j = 0; j < 4; ++j)
#pragma unroll
        for (int r = 0; r < 4; ++r)
            lg[j][r] = acc_hh[j][r] + acc_md[j][r] * (1.0f / 2048.0f);

    float* rbuf = (float*)&lw[0][0];   // 16 KB scratch, DMA fully drained
    if (h == 1) {
#pragma unroll
        for (int j = 0; j < 4; ++j)
#pragma unroll
            for (int r = 0; r < 4; ++r)
                rbuf[t * 1024 + (j * 4 + r) * 64 + lane] = lg[j][r];
    }
    __syncthreads();
    if (h == 1) return;

#pragma unroll
    for (int j = 0; j < 4; ++j) {
        const float bj = bias[j * 16 + mrow];
#pragma unroll
        for (int r = 0; r < 4; ++r)
            lg[j][r] += rbuf[t * 1024 + (j * 4 + r) * 64 + lane] + bj;
    }

    // ---- epilogue: lane owns tokens t0 + quad*4 + r, experts j*16 + mrow ----
    const int c = mrow;
#pragma unroll
    for (int r = 0; r < 4; ++r) {
        const int trow = t0 + quad * 4 + r;

        float m = lg[0][r];
#pragma unroll
        for (int j = 1; j < 4; ++j) m = fmaxf(m, lg[j][r]);
#pragma unroll
        for (int off = 1; off <= 8; off <<= 1) m = fmaxf(m, __shfl_xor(m, off));

        float pj[4], s = 0.0f;
#pragma unroll
        for (int j = 0; j < 4; ++j) { pj[j] = __expf(lg[j][r] - m); s += pj[j]; }
#pragma unroll
        for (int off = 1; off <= 8; off <<= 1) s += __shfl_xor(s, off);
        const float rinv = 1.0f / s;

        // stable top-2 on logits (tie -> lower expert index)
        float v1 = -1e30f, v2 = -1e30f; int i1 = -1, i2 = -1;
#pragma unroll
        for (int j = 0; j < 4; ++j) {
            float v = lg[j][r]; int e = j * 16 + c;
            if (v > v1 || (v == v1 && e < i1)) { v2 = v1; i2 = i1; v1 = v; i1 = e; }
            else if (v > v2 || (v == v2 && e < i2)) { v2 = v; i2 = e; }
        }
#pragma unroll
        for (int off = 1; off <= 8; off <<= 1) {
            float u1 = __shfl_xor(v1, off); int q1 = __shfl_xor(i1, off);
            float u2 = __shfl_xor(v2, off); int q2 = __shfl_xor(i2, off);
            if (u1 > v1 || (u1 == v1 && q1 < i1)) {
                if (v1 > u2 || (v1 == u2 && i1 < q2)) { v2 = v1; i2 = i1; }
                else                                   { v2 = u2; i2 = q2; }
                v1 = u1; i1 = q1;
            } else {
                if (u1 > v2 || (u1 == v2 && q1 < i2)) { v2 = u1; i2 = q1; }
            }
        }

#pragma unroll
        for (int j = 0; j < 4; ++j) {
            const int col = j * 16 + c;
            const size_t o = (size_t)trow * NEXP + col;
            out[o]           = (col == i1 || col == i2) ? 1.0f : 0.0f;
            out[PSTRIDE + o] = pj[j] * rinv;
        }
    }
}

extern "C" void kernel_launch(void* const* d_in, const int* in_sizes, int n_in,
                              void* d_out, int out_size, void* d_ws, size_t ws_size,
                              hipStream_t stream) {
    const float* x = (const float*)d_in[0];   // [4,4096,2048] f32
    const float* W = (const float*)d_in[1];   // [64,2048] f32
    const float* b = (const float*)d_in[2];   // [64] f32
    (void)in_sizes; (void)n_in; (void)out_size; (void)ws_size;
    float* out = (float*)d_out;               // [masks | probs]

    _Float16* ws = (_Float16*)d_ws;           // 16 slices x 32 KB = 512 KB

    hipLaunchKernelGGL(wconv_kernel, dim3(128), dim3(256), 0, stream, W, ws);
    hipLaunchKernelGGL(router_kernel, dim3(NTOK / 64), dim3(512), 0, stream, x, ws, b, out);
}